// Round 9
// baseline (341.236 us; speedup 1.0000x reference)
//
#include <hip/hip_runtime.h>

typedef unsigned short u16;
typedef unsigned int   u32;
typedef __attribute__((ext_vector_type(4))) float  f32x4;
typedef __attribute__((ext_vector_type(8))) __bf16 bf16x8;

#define EMBED 2048
#define NH    16
#define NKV   4
#define HD    128
#define TT    2048
#define BB    2
#define MROWS (BB*TT)
#define QSCALE 0.08838834764831845f

#define QELEMS ((size_t)BB*NH*TT*HD)
#define KELEMS ((size_t)BB*NKV*TT*HD)

#define AS1(p) (__attribute__((address_space(1))) void*)(void*)(p)
#define AS3(p) (__attribute__((address_space(3))) void*)(void*)(p)

// NOTE (r7 post-mortem): 256x256 8-phase GEMM tried for QKV (192 blocks) was
// -10us vs this 128^2 structure — 75% CU coverage + 1 block/CU killed the
// template's gain (template verified at >=256 blocks). Keep 128^2 here.

static __device__ __forceinline__ u16 f2b(float f){
  union { float f; u32 u; } v; v.f = f;
  u32 u = v.u;
  u32 r = u + 0x7FFFu + ((u >> 16) & 1u);   // RNE
  return (u16)(r >> 16);
}

// ---------------- fp32 -> bf16 convert (x) ----------------
__global__ __launch_bounds__(256) void cvt_f32_bf16(const float* __restrict__ in,
                                                    u16* __restrict__ out, int n4){
  int i = blockIdx.x * 256 + threadIdx.x;
  if (i >= n4) return;
  float4 v = ((const float4*)in)[i];
  uint2 o;
  o.x = (u32)f2b(v.x) | ((u32)f2b(v.y) << 16);
  o.y = (u32)f2b(v.z) | ((u32)f2b(v.w) << 16);
  ((uint2*)out)[i] = o;
}

// ---------------- fp32 [R][C] -> bf16 [C][R], two matrices per launch (z-dim) ----------------
__global__ __launch_bounds__(256) void trans_w2(const float* __restrict__ in0, u16* __restrict__ out0,
                                                const float* __restrict__ in1, u16* __restrict__ out1,
                                                int R, int C){
  const float* in = blockIdx.z ? in1 : in0;
  u16*        out = blockIdx.z ? out1 : out0;
  __shared__ u16 tile[32][33];
  int c0 = blockIdx.x * 32, r0 = blockIdx.y * 32;
  int tx = threadIdx.x & 31, ty = threadIdx.x >> 5;   // 32 x 8
  #pragma unroll
  for (int j = 0; j < 32; j += 8)
    tile[ty + j][tx] = f2b(in[(size_t)(r0 + ty + j) * C + c0 + tx]);
  __syncthreads();
  #pragma unroll
  for (int j = 0; j < 32; j += 8)
    out[(size_t)(c0 + ty + j) * R + r0 + tx] = tile[tx][ty + j];
}

// ---------------- bf16 [BH][T][D] -> [BH][D][T]  (V for PV fragment reads) ----------------
__global__ __launch_bounds__(256) void trans_v(const u16* __restrict__ in,
                                               u16* __restrict__ out){
  __shared__ u16 tile[32][33];
  int d0 = (blockIdx.x & 3) * 32;            // D/32 = 4
  int t0 = ((blockIdx.x >> 2) & 63) * 32;    // T/32 = 64
  int bh = blockIdx.x >> 8;                  // B*NKV = 8
  const u16* ip = in  + (size_t)bh * TT * HD;
  u16*       op = out + (size_t)bh * TT * HD;
  int tx = threadIdx.x & 31, ty = threadIdx.x >> 5;
  #pragma unroll
  for (int j = 0; j < 32; j += 8)
    tile[ty + j][tx] = ip[(size_t)(t0 + ty + j) * HD + d0 + tx];
  __syncthreads();
  #pragma unroll
  for (int j = 0; j < 32; j += 8)
    op[(size_t)(d0 + ty + j) * TT + t0 + tx] = tile[tx][ty + j];
}

// ---------------- bf16 GEMM: C[M,N] = A[M,K] * Bt[N,K]^T (128^2, m97 structure) ----------------
// EPI 0: fp32 [M][N] out.
// EPI 2: fused QKV split — outp is the contiguous qkv buffer; block column band
//        (128 wide) maps to exactly one head, so routing is block-uniform.
template<int EPI>
__global__ __launch_bounds__(256)
void gemm_bt(const u16* __restrict__ A, const u16* __restrict__ Bt,
             void* __restrict__ outp, int N, int K){
  __shared__ __align__(16) u16 As[2][128*32];
  __shared__ __align__(16) u16 Bs[2][128*32];
  int tid  = threadIdx.x;
  int lane = tid & 63, w = tid >> 6;
  int nwg = gridDim.x;
  int bid = blockIdx.x;
  bid = (bid & 7) * (nwg >> 3) + (bid >> 3);      // XCD swizzle (nwg % 8 == 0 always here)
  int nbn  = N >> 7;
  int brow = (bid / nbn) * 128;
  int bcol = (bid % nbn) * 128;

  auto stage = [&](int buf, int kt){
    #pragma unroll
    for (int j = 0; j < 2; ++j){
      int boff  = w * 2048 + j * 1024;            // byte offset into 8KB tile (wave-uniform)
      int chunk = (boff >> 4) + lane;             // this lane's 16B chunk id
      int row   = chunk >> 2;                     // 4 chunks per 64B row
      int cko   = chunk & 3;
      const u16* ga = A  + (size_t)(brow + row) * K + kt + cko * 8;
      const u16* gb = Bt + (size_t)(bcol + row) * K + kt + cko * 8;
      __builtin_amdgcn_global_load_lds(AS1(ga), AS3(&As[buf][boff >> 1]), 16, 0, 0);
      __builtin_amdgcn_global_load_lds(AS1(gb), AS3(&Bs[buf][boff >> 1]), 16, 0, 0);
    }
  };

  int lr = lane & 15, lg = lane >> 4, lk = lg * 8;
  int wr = (w >> 1) * 64, wc = (w & 1) * 64;

  f32x4 acc[4][4];
  #pragma unroll
  for (int m = 0; m < 4; ++m)
    #pragma unroll
    for (int n = 0; n < 4; ++n)
      #pragma unroll
      for (int r = 0; r < 4; ++r) acc[m][n][r] = 0.f;

  int NT = K >> 5;
  stage(0, 0);
  asm volatile("s_waitcnt vmcnt(0)" ::: "memory");
  __syncthreads();
  int cur = 0;
  for (int t = 0; t < NT; ++t){
    if (t + 1 < NT) stage(cur ^ 1, (t + 1) * 32);
    const u16* as = As[cur];
    const u16* bs = Bs[cur];
    bf16x8 af[4], bfv[4];
    #pragma unroll
    for (int m = 0; m < 4; ++m) af[m]  = *(const bf16x8*)(as + (wr + m*16 + lr)*32 + lk);
    #pragma unroll
    for (int n = 0; n < 4; ++n) bfv[n] = *(const bf16x8*)(bs + (wc + n*16 + lr)*32 + lk);
    #pragma unroll
    for (int m = 0; m < 4; ++m)
      #pragma unroll
      for (int n = 0; n < 4; ++n)
        acc[m][n] = __builtin_amdgcn_mfma_f32_16x16x32_bf16(af[m], bfv[n], acc[m][n], 0, 0, 0);
    asm volatile("s_waitcnt vmcnt(0)" ::: "memory");
    __syncthreads();
    cur ^= 1;
  }

  if (EPI == 0){
    float* o = (float*)outp;
    #pragma unroll
    for (int m = 0; m < 4; ++m)
      #pragma unroll
      for (int r = 0; r < 4; ++r){
        int rowg = brow + wr + m*16 + lg*4 + r;
        float* orow = o + (size_t)rowg * N + bcol + wc + lr;
        #pragma unroll
        for (int n = 0; n < 4; ++n) orow[n*16] = acc[m][n][r];
      }
  } else {
    // EPI 2: route this block's 128-wide column band to q / k / v
    u16* qb = (u16*)outp;
    u16* kb = qb + QELEMS;
    u16* vb = kb + KELEMS;
    int hb = bcol >> 7;                 // 0..23
    int b  = brow >> 11;
    u16* hp; float s;
    if (hb < 16)      { hp = qb + ((size_t)(b*NH  +  hb     )) * TT * HD; s = QSCALE; }
    else if (hb < 20) { hp = kb + ((size_t)(b*NKV + (hb-16))) * TT * HD; s = 1.0f; }
    else              { hp = vb + ((size_t)(b*NKV + (hb-20))) * TT * HD; s = 1.0f; }
    #pragma unroll
    for (int m = 0; m < 4; ++m)
      #pragma unroll
      for (int r = 0; r < 4; ++r){
        int t = (brow + wr + m*16 + lg*4 + r) & (TT - 1);
        #pragma unroll
        for (int n = 0; n < 4; ++n){
          int d = wc + n*16 + lr;
          hp[(size_t)t * HD + d] = f2b(acc[m][n][r] * s);
        }
      }
  }
}

// ---------------- flash attention v3: SINGLE-buffered K/V (44 KB -> 3 blocks/CU), 1024 blocks ----
// Mechanism: per-block schedule is a rigid latency chain (3 prior nulls, all pipes <40%);
// raise co-resident blocks 2->3/CU and blocks 512->1024 so other blocks cover the chain.
// Staging exposed once per step (L2-resident K/V, ~300-500cy) — covered by TLP.
__global__ __launch_bounds__(256)
void attn_kernel(const u16* __restrict__ qb, const u16* __restrict__ kb,
                 const u16* __restrict__ vtb, u16* __restrict__ ob){
  __shared__ __align__(16) u16 Ks[64*128];      // [kv 64][d 128], chunk-swizzled (16 KB)
  __shared__ __align__(16) u16 Vs[128*64];      // [d 128][kv 64], chunk-swizzled (16 KB)
  __shared__ __align__(16) u16 pl[4][16*88];    // per-wave P scratch (11 KB)
  int tid = threadIdx.x, lane = tid & 63, w = tid >> 6;
  int nwg = gridDim.x;                          // 1024
  int bid = blockIdx.x;
  bid = (bid & 7) * (nwg >> 3) + (bid >> 3);    // chunked XCD swizzle: (b,hkv) groups cluster
  int qt = bid & 31;
  int h  = (bid >> 5) & 15;
  int b  = bid >> 9;
  int hkv = h >> 2;                             // GROUP = 4, consecutive repeat
  int lr = lane & 15, lg = lane >> 4, lk = lg * 8;
  int sw = (lr & 7) << 3;                       // read-side XOR (elements)

  const u16* qbase = qb  + ((size_t)b * NH  + h  ) * TT * HD;
  const u16* kbase = kb  + ((size_t)b * NKV + hkv) * TT * HD;
  const u16* vbase = vtb + ((size_t)b * NKV + hkv) * HD * TT;

  auto stage = [&](int kt){
    #pragma unroll
    for (int i = 0; i < 4; ++i){
      int c  = i * 256 + tid;                   // 16B-chunk id (per-lane)
      int ub = (i * 256 + w * 64) * 8;          // wave-uniform LDS elem base
      int kr = c >> 4, kc = (c & 15) ^ (kr & 7);        // K: 16 chunks per 256B row
      const u16* gk = kbase + (size_t)(kt * 64 + kr) * HD + kc * 8;
      __builtin_amdgcn_global_load_lds(AS1(gk), AS3(&Ks[ub]), 16, 0, 0);
      int vr = c >> 3, vc = (c & 7) ^ (vr & 7);         // V: 8 chunks per 128B row
      const u16* gv = vbase + (size_t)vr * TT + kt * 64 + vc * 8;
      __builtin_amdgcn_global_load_lds(AS1(gv), AS3(&Vs[ub]), 16, 0, 0);
    }
  };

  __bf16* plw = (__bf16*)pl[w];
  int q0 = qt * 64 + w * 16;

  bf16x8 aq[4];
  #pragma unroll
  for (int s = 0; s < 4; ++s)
    aq[s] = *(const bf16x8*)(qbase + (size_t)(q0 + lr) * HD + s*32 + lk);

  f32x4 o_acc[8];
  #pragma unroll
  for (int dt = 0; dt < 8; ++dt)
    #pragma unroll
    for (int r = 0; r < 4; ++r) o_acc[dt][r] = 0.f;
  float mrow[4], lrow[4];
  #pragma unroll
  for (int r = 0; r < 4; ++r){ mrow[r] = -1e30f; lrow[r] = 0.f; }

  stage(0);
  asm volatile("s_waitcnt vmcnt(0)" ::: "memory");
  __builtin_amdgcn_s_barrier();

  for (int kt = 0; kt <= qt; ++kt){
    // ---- scores = Q K^T (16 x 64) from swizzled LDS ----
    f32x4 sc[4];
    #pragma unroll
    for (int c = 0; c < 4; ++c)
      #pragma unroll
      for (int r = 0; r < 4; ++r) sc[c][r] = 0.f;
    __builtin_amdgcn_s_setprio(1);
    #pragma unroll
    for (int c = 0; c < 4; ++c){
      const u16* kp = Ks + (c*16 + lr) * 128;
      #pragma unroll
      for (int s = 0; s < 4; ++s){
        bf16x8 kf = *(const bf16x8*)(kp + (((s*32) + lk) ^ sw));
        sc[c] = __builtin_amdgcn_mfma_f32_16x16x32_bf16(aq[s], kf, sc[c], 0, 0, 0);
      }
    }
    __builtin_amdgcn_s_setprio(0);
    if (kt == qt){
      #pragma unroll
      for (int c = 0; c < 4; ++c){
        int kvg = kt*64 + c*16 + lr;
        #pragma unroll
        for (int r = 0; r < 4; ++r){
          int qg = q0 + lg*4 + r;               // C-layout row
          if (kvg > qg) sc[c][r] = -1e30f;
        }
      }
    }
    // ---- online softmax with defer-max (T13) ----
    float tmv[4];
    #pragma unroll
    for (int r = 0; r < 4; ++r){
      float tm = fmaxf(fmaxf(sc[0][r], sc[1][r]), fmaxf(sc[2][r], sc[3][r]));
      tm = fmaxf(tm, __shfl_xor(tm, 1));
      tm = fmaxf(tm, __shfl_xor(tm, 2));
      tm = fmaxf(tm, __shfl_xor(tm, 4));
      tm = fmaxf(tm, __shfl_xor(tm, 8));
      tmv[r] = tm;
    }
    bool need = (tmv[0] > mrow[0] + 8.f) || (tmv[1] > mrow[1] + 8.f) ||
                (tmv[2] > mrow[2] + 8.f) || (tmv[3] > mrow[3] + 8.f);
    if (__any(need ? 1 : 0)){
      #pragma unroll
      for (int r = 0; r < 4; ++r){
        float mnew  = fmaxf(mrow[r], tmv[r]);
        float alpha = __expf(mrow[r] - mnew);
        mrow[r] = mnew;
        lrow[r] *= alpha;
        #pragma unroll
        for (int dt = 0; dt < 8; ++dt) o_acc[dt][r] *= alpha;
      }
    }
    #pragma unroll
    for (int r = 0; r < 4; ++r){
      float rs = 0.f;
      #pragma unroll
      for (int c = 0; c < 4; ++c){
        float p = __expf(sc[c][r] - mrow[r]);
        rs += p;
        plw[(lg*4 + r)*88 + c*16 + lr] = (__bf16)p;
      }
      rs += __shfl_xor(rs, 1); rs += __shfl_xor(rs, 2);
      rs += __shfl_xor(rs, 4); rs += __shfl_xor(rs, 8);
      lrow[r] += rs;
    }
    asm volatile("s_waitcnt lgkmcnt(0)" ::: "memory");
    // ---- O += P V from swizzled LDS ----
    bf16x8 pa[2];
    #pragma unroll
    for (int kk = 0; kk < 2; ++kk)
      pa[kk] = *(const bf16x8*)((const u16*)plw + lr*88 + kk*32 + lk);
    __builtin_amdgcn_s_setprio(1);
    #pragma unroll
    for (int dt = 0; dt < 8; ++dt){
      const u16* vp = Vs + (dt*16 + lr) * 64;
      #pragma unroll
      for (int kk = 0; kk < 2; ++kk){
        bf16x8 vf = *(const bf16x8*)(vp + (((kk*32) + lk) ^ sw));
        o_acc[dt] = __builtin_amdgcn_mfma_f32_16x16x32_bf16(pa[kk], vf, o_acc[dt], 0, 0, 0);
      }
    }
    __builtin_amdgcn_s_setprio(0);
    // ---- single-buffer handoff: all reads of tile kt done -> restage ----
    if (kt < qt){
      __builtin_amdgcn_s_barrier();             // every wave finished reading Ks/Vs
      stage(kt + 1);
      asm volatile("s_waitcnt vmcnt(0)" ::: "memory");
      __builtin_amdgcn_s_barrier();             // tile kt+1 fully resident
    }
  }
  // ---- epilogue: ob[b][t][h*128+d] = O / l ----
  #pragma unroll
  for (int r = 0; r < 4; ++r){
    float inv = 1.0f / lrow[r];
    int t = q0 + lg*4 + r;
    size_t base = ((size_t)b * TT + t) * EMBED + h * HD;
    #pragma unroll
    for (int dt = 0; dt < 8; ++dt)
      ob[base + dt*16 + lr] = f2b(o_acc[dt][r] * inv);
  }
}

extern "C" void kernel_launch(void* const* d_in, const int* in_sizes, int n_in,
                              void* d_out, int out_size, void* d_ws, size_t ws_size,
                              hipStream_t stream){
  const float* x  = (const float*)d_in[0];
  const float* Wq = (const float*)d_in[1];
  const float* Wk = (const float*)d_in[2];
  const float* Wv = (const float*)d_in[3];
  const float* Wo = (const float*)d_in[4];

  char* ws = (char*)d_ws;
  size_t off = 0;
  auto alloc = [&](size_t bytes){ void* p = ws + off; off += (bytes + 255) & ~(size_t)255; return p; };
  u16* xb    = (u16*)alloc((size_t)MROWS * EMBED * 2);
  u16* Wqkvt = (u16*)alloc((size_t)3072 * EMBED * 2);        // rows: 0..2047 Wq, 2048..2559 Wk, 2560..3071 Wv
  u16* Wot   = (u16*)alloc((size_t)EMBED * EMBED * 2);
  u16* qkv   = (u16*)alloc((QELEMS + 2*KELEMS) * 2);          // q | k | v contiguous
  u16* vtb   = (u16*)alloc(KELEMS * 2);
  u16* ob    = (u16*)alloc((size_t)MROWS * EMBED * 2);

  u16* qb = qkv;
  u16* kb = qb + QELEMS;
  u16* vb = kb + KELEMS;

  cvt_f32_bf16<<<(MROWS*EMBED/4 + 255)/256, 256, 0, stream>>>(x, xb, MROWS*EMBED/4);
  trans_w2<<<dim3(EMBED/32, EMBED/32, 2), 256, 0, stream>>>(Wq, Wqkvt, Wo, Wot, EMBED, EMBED);
  trans_w2<<<dim3(512/32,   EMBED/32, 2), 256, 0, stream>>>(Wk, Wqkvt + (size_t)2048*EMBED,
                                                            Wv, Wqkvt + (size_t)2560*EMBED, EMBED, 512);

  gemm_bt<2><<<(MROWS/128)*(3072/128), 256, 0, stream>>>(xb, Wqkvt, qkv, 3072, EMBED);
  trans_v<<<4*64*BB*NKV, 256, 0, stream>>>(vb, vtb);

  attn_kernel<<<BB*NH*32, 256, 0, stream>>>(qb, kb, vtb, ob);

  gemm_bt<0><<<(MROWS/128)*(EMBED/128), 256, 0, stream>>>(ob, Wot, d_out, EMBED, EMBED);
}

// Round 10
// 313.319 us; speedup vs baseline: 1.0891x; 1.0891x over previous
//
#include <hip/hip_runtime.h>

typedef unsigned short u16;
typedef unsigned int   u32;
typedef __attribute__((ext_vector_type(4))) float  f32x4;
typedef __attribute__((ext_vector_type(8))) __bf16 bf16x8;

#define EMBED 2048
#define NH    16
#define NKV   4
#define HD    128
#define TT    2048
#define BB    2
#define MROWS (BB*TT)
#define QSCALE 0.08838834764831845f

#define QELEMS ((size_t)BB*NH*TT*HD)
#define KELEMS ((size_t)BB*NKV*TT*HD)

#define AS1(p) (__attribute__((address_space(1))) void*)(void*)(p)
#define AS3(p) (__attribute__((address_space(3))) void*)(void*)(p)

// NOTE (r7): 256^2 8-phase GEMM at 192 blocks was -10us (75% CU coverage, 1 blk/CU) — keep 128^2.
// NOTE (r9): single-buffer attn (3 blk/CU attempt) was -24us — occupancy didn't rise; limiter is
//            the per-CU DS pipe, not TLP. r10: cut DS ops via swapped-QK^T in-register softmax.

static __device__ __forceinline__ u16 f2b(float f){
  union { float f; u32 u; } v; v.f = f;
  u32 u = v.u;
  u32 r = u + 0x7FFFu + ((u >> 16) & 1u);   // RNE
  return (u16)(r >> 16);
}

// ---------------- fp32 -> bf16 convert (x) ----------------
__global__ __launch_bounds__(256) void cvt_f32_bf16(const float* __restrict__ in,
                                                    u16* __restrict__ out, int n4){
  int i = blockIdx.x * 256 + threadIdx.x;
  if (i >= n4) return;
  float4 v = ((const float4*)in)[i];
  uint2 o;
  o.x = (u32)f2b(v.x) | ((u32)f2b(v.y) << 16);
  o.y = (u32)f2b(v.z) | ((u32)f2b(v.w) << 16);
  ((uint2*)out)[i] = o;
}

// ---------------- fp32 [R][C] -> bf16 [C][R], two matrices per launch (z-dim) ----------------
__global__ __launch_bounds__(256) void trans_w2(const float* __restrict__ in0, u16* __restrict__ out0,
                                                const float* __restrict__ in1, u16* __restrict__ out1,
                                                int R, int C){
  const float* in = blockIdx.z ? in1 : in0;
  u16*        out = blockIdx.z ? out1 : out0;
  __shared__ u16 tile[32][33];
  int c0 = blockIdx.x * 32, r0 = blockIdx.y * 32;
  int tx = threadIdx.x & 31, ty = threadIdx.x >> 5;   // 32 x 8
  #pragma unroll
  for (int j = 0; j < 32; j += 8)
    tile[ty + j][tx] = f2b(in[(size_t)(r0 + ty + j) * C + c0 + tx]);
  __syncthreads();
  #pragma unroll
  for (int j = 0; j < 32; j += 8)
    out[(size_t)(c0 + ty + j) * R + r0 + tx] = tile[tx][ty + j];
}

// ---------------- bf16 [BH][T][D] -> [BH][D][T]  (V for PV fragment reads) ----------------
__global__ __launch_bounds__(256) void trans_v(const u16* __restrict__ in,
                                               u16* __restrict__ out){
  __shared__ u16 tile[32][33];
  int d0 = (blockIdx.x & 3) * 32;            // D/32 = 4
  int t0 = ((blockIdx.x >> 2) & 63) * 32;    // T/32 = 64
  int bh = blockIdx.x >> 8;                  // B*NKV = 8
  const u16* ip = in  + (size_t)bh * TT * HD;
  u16*       op = out + (size_t)bh * TT * HD;
  int tx = threadIdx.x & 31, ty = threadIdx.x >> 5;
  #pragma unroll
  for (int j = 0; j < 32; j += 8)
    tile[ty + j][tx] = ip[(size_t)(t0 + ty + j) * HD + d0 + tx];
  __syncthreads();
  #pragma unroll
  for (int j = 0; j < 32; j += 8)
    op[(size_t)(d0 + ty + j) * TT + t0 + tx] = tile[tx][ty + j];
}

// ---------------- bf16 GEMM: C[M,N] = A[M,K] * Bt[N,K]^T (128^2, m97 structure) ----------------
template<int EPI>
__global__ __launch_bounds__(256)
void gemm_bt(const u16* __restrict__ A, const u16* __restrict__ Bt,
             void* __restrict__ outp, int N, int K){
  __shared__ __align__(16) u16 As[2][128*32];
  __shared__ __align__(16) u16 Bs[2][128*32];
  int tid  = threadIdx.x;
  int lane = tid & 63, w = tid >> 6;
  int nwg = gridDim.x;
  int bid = blockIdx.x;
  bid = (bid & 7) * (nwg >> 3) + (bid >> 3);      // XCD swizzle (nwg % 8 == 0 always here)
  int nbn  = N >> 7;
  int brow = (bid / nbn) * 128;
  int bcol = (bid % nbn) * 128;

  auto stage = [&](int buf, int kt){
    #pragma unroll
    for (int j = 0; j < 2; ++j){
      int boff  = w * 2048 + j * 1024;
      int chunk = (boff >> 4) + lane;
      int row   = chunk >> 2;
      int cko   = chunk & 3;
      const u16* ga = A  + (size_t)(brow + row) * K + kt + cko * 8;
      const u16* gb = Bt + (size_t)(bcol + row) * K + kt + cko * 8;
      __builtin_amdgcn_global_load_lds(AS1(ga), AS3(&As[buf][boff >> 1]), 16, 0, 0);
      __builtin_amdgcn_global_load_lds(AS1(gb), AS3(&Bs[buf][boff >> 1]), 16, 0, 0);
    }
  };

  int lr = lane & 15, lg = lane >> 4, lk = lg * 8;
  int wr = (w >> 1) * 64, wc = (w & 1) * 64;

  f32x4 acc[4][4];
  #pragma unroll
  for (int m = 0; m < 4; ++m)
    #pragma unroll
    for (int n = 0; n < 4; ++n)
      #pragma unroll
      for (int r = 0; r < 4; ++r) acc[m][n][r] = 0.f;

  int NT = K >> 5;
  stage(0, 0);
  asm volatile("s_waitcnt vmcnt(0)" ::: "memory");
  __syncthreads();
  int cur = 0;
  for (int t = 0; t < NT; ++t){
    if (t + 1 < NT) stage(cur ^ 1, (t + 1) * 32);
    const u16* as = As[cur];
    const u16* bs = Bs[cur];
    bf16x8 af[4], bfv[4];
    #pragma unroll
    for (int m = 0; m < 4; ++m) af[m]  = *(const bf16x8*)(as + (wr + m*16 + lr)*32 + lk);
    #pragma unroll
    for (int n = 0; n < 4; ++n) bfv[n] = *(const bf16x8*)(bs + (wc + n*16 + lr)*32 + lk);
    #pragma unroll
    for (int m = 0; m < 4; ++m)
      #pragma unroll
      for (int n = 0; n < 4; ++n)
        acc[m][n] = __builtin_amdgcn_mfma_f32_16x16x32_bf16(af[m], bfv[n], acc[m][n], 0, 0, 0);
    asm volatile("s_waitcnt vmcnt(0)" ::: "memory");
    __syncthreads();
    cur ^= 1;
  }

  if (EPI == 0){
    float* o = (float*)outp;
    #pragma unroll
    for (int m = 0; m < 4; ++m)
      #pragma unroll
      for (int r = 0; r < 4; ++r){
        int rowg = brow + wr + m*16 + lg*4 + r;
        float* orow = o + (size_t)rowg * N + bcol + wc + lr;
        #pragma unroll
        for (int n = 0; n < 4; ++n) orow[n*16] = acc[m][n][r];
      }
  } else {
    u16* qb = (u16*)outp;
    u16* kb = qb + QELEMS;
    u16* vb = kb + KELEMS;
    int hb = bcol >> 7;                 // 0..23
    int b  = brow >> 11;
    u16* hp; float s;
    if (hb < 16)      { hp = qb + ((size_t)(b*NH  +  hb     )) * TT * HD; s = QSCALE; }
    else if (hb < 20) { hp = kb + ((size_t)(b*NKV + (hb-16))) * TT * HD; s = 1.0f; }
    else              { hp = vb + ((size_t)(b*NKV + (hb-20))) * TT * HD; s = 1.0f; }
    #pragma unroll
    for (int m = 0; m < 4; ++m)
      #pragma unroll
      for (int r = 0; r < 4; ++r){
        int t = (brow + wr + m*16 + lg*4 + r) & (TT - 1);
        #pragma unroll
        for (int n = 0; n < 4; ++n){
          int d = wc + n*16 + lr;
          hp[(size_t)t * HD + d] = f2b(acc[m][n][r] * s);
        }
      }
  }
}

// ---------------- flash attention v4: swapped QK^T, fully in-register softmax ----------------
// mfma(K,Q) -> lane holds P[q=lane&15][kv=16c+4g+r] (g=lane>>4). Row reduce = in-lane + 2 shfl.
// P -> PV A-fragments via cvt_pk_bf16 + 12 shfl_xor register permutation (no LDS P round-trip).
// Double-buffered K/V (XOR-swizzled), paired q-tiles, counted-vmcnt staging (r6 schedule).
__global__ __launch_bounds__(256)
void attn_kernel(const u16* __restrict__ qb, const u16* __restrict__ kb,
                 const u16* __restrict__ vtb, u16* __restrict__ ob){
  __shared__ __align__(16) u16 Ks[2][64*128];   // [kv 64][d 128], chunk-swizzled
  __shared__ __align__(16) u16 Vs[2][128*64];   // [d 128][kv 64], chunk-swizzled
  int tid = threadIdx.x, lane = tid & 63, w = tid >> 6;
  int nwg = gridDim.x;                          // 512
  int bid = blockIdx.x;
  bid = (bid & 7) * (nwg >> 3) + (bid >> 3);    // chunked XCD swizzle
  int pair = bid & 15;
  int h    = (bid >> 4) & 15;
  int b    = bid >> 8;
  int hkv  = h >> 2;
  int j  = lane & 15, g = lane >> 4, lk = g * 8;
  int gh = g >> 1;
  int sw = (j & 7) << 3;                        // read-side XOR (elements)

  const u16* qbase = qb  + ((size_t)b * NH  + h  ) * TT * HD;
  const u16* kbase = kb  + ((size_t)b * NKV + hkv) * TT * HD;
  const u16* vbase = vtb + ((size_t)b * NKV + hkv) * HD * TT;

  auto stage = [&](int buf, int kt){
    #pragma unroll
    for (int i = 0; i < 4; ++i){
      int c  = i * 256 + tid;
      int ub = (i * 256 + w * 64) * 8;
      int kr = c >> 4, kc = (c & 15) ^ (kr & 7);
      const u16* gk = kbase + (size_t)(kt * 64 + kr) * HD + kc * 8;
      __builtin_amdgcn_global_load_lds(AS1(gk), AS3(&Ks[buf][ub]), 16, 0, 0);
      int vr = c >> 3, vc = (c & 7) ^ (vr & 7);
      const u16* gv = vbase + (size_t)vr * TT + kt * 64 + vc * 8;
      __builtin_amdgcn_global_load_lds(AS1(gv), AS3(&Vs[buf][ub]), 16, 0, 0);
    }
  };

  for (int half = 0; half < 2; ++half){
    int qt = half ? (31 - pair) : pair;
    int q0 = qt * 64 + w * 16;

    bf16x8 aq[4];
    #pragma unroll
    for (int s = 0; s < 4; ++s)
      aq[s] = *(const bf16x8*)(qbase + (size_t)(q0 + j) * HD + s*32 + lk);

    f32x4 o_acc[8];
    #pragma unroll
    for (int dt = 0; dt < 8; ++dt)
      #pragma unroll
      for (int r = 0; r < 4; ++r) o_acc[dt][r] = 0.f;
    float mrow = -1e30f, lrow = 0.f;            // stats for q = q0 + j (per-lane)

    __builtin_amdgcn_s_barrier();               // close previous half's reads
    stage(0, 0);
    int cur = 0;
    for (int kt = 0; kt <= qt; ++kt){
      __builtin_amdgcn_s_barrier();             // all waves done reading buf cur^1
      if (kt < qt){
        stage(cur ^ 1, kt + 1);
        asm volatile("s_waitcnt vmcnt(8)" ::: "memory");   // stage(kt) landed
      } else {
        asm volatile("s_waitcnt vmcnt(0)" ::: "memory");
      }
      __builtin_amdgcn_s_barrier();             // buf cur fully populated

      // ---- scores (swapped): sc[c] = K_c * Q -> D[row=kv][col=q] ----
      const u16* ks = Ks[cur];
      f32x4 sc[4];
      #pragma unroll
      for (int c = 0; c < 4; ++c)
        #pragma unroll
        for (int r = 0; r < 4; ++r) sc[c][r] = 0.f;
      __builtin_amdgcn_s_setprio(1);
      #pragma unroll
      for (int c = 0; c < 4; ++c){
        const u16* kp = ks + (c*16 + j) * 128;  // A-operand row = lane&15 (same addr as before)
        #pragma unroll
        for (int s = 0; s < 4; ++s){
          bf16x8 kf = *(const bf16x8*)(kp + (((s*32) + lk) ^ sw));
          sc[c] = __builtin_amdgcn_mfma_f32_16x16x32_bf16(kf, aq[s], sc[c], 0, 0, 0);
        }
      }
      __builtin_amdgcn_s_setprio(0);
      if (kt == qt){
        int qg = q0 + j;
        #pragma unroll
        for (int c = 0; c < 4; ++c)
          #pragma unroll
          for (int r = 0; r < 4; ++r)
            if (kt*64 + c*16 + g*4 + r > qg) sc[c][r] = -1e30f;
      }
      // ---- row stats: in-lane over 16, then 2 shfl across the 4 lane-groups ----
      float tm = fmaxf(fmaxf(fmaxf(sc[0][0], sc[0][1]), fmaxf(sc[0][2], sc[0][3])),
                       fmaxf(fmaxf(sc[1][0], sc[1][1]), fmaxf(sc[1][2], sc[1][3])));
      tm = fmaxf(tm, fmaxf(fmaxf(fmaxf(sc[2][0], sc[2][1]), fmaxf(sc[2][2], sc[2][3])),
                           fmaxf(fmaxf(sc[3][0], sc[3][1]), fmaxf(sc[3][2], sc[3][3]))));
      tm = fmaxf(tm, __shfl_xor(tm, 16));
      tm = fmaxf(tm, __shfl_xor(tm, 32));
      // ---- defer-max (T13) ----
      if (__any((tm > mrow + 8.f) ? 1 : 0)){
        float mnew  = fmaxf(mrow, tm);
        float alpha = __expf(mrow - mnew);
        mrow = mnew;
        lrow *= alpha;
        #pragma unroll
        for (int r = 0; r < 4; ++r){
          float ar = __shfl(alpha, (lane & 48) | (g*4 + r));  // alpha for o_acc row q=g*4+r
          #pragma unroll
          for (int dt = 0; dt < 8; ++dt) o_acc[dt][r] *= ar;
        }
      }
      float rs = 0.f;
      #pragma unroll
      for (int c = 0; c < 4; ++c)
        #pragma unroll
        for (int r = 0; r < 4; ++r){
          float p = __expf(sc[c][r] - mrow);
          sc[c][r] = p;
          rs += p;
        }
      rs += __shfl_xor(rs, 16);
      rs += __shfl_xor(rs, 32);
      lrow += rs;
      // ---- pack P to bf16 pairs: pk[c][h] = (kv 16c+4g+2h, +1) for q=j ----
      u32 pk[4][2];
      #pragma unroll
      for (int c = 0; c < 4; ++c){
        asm("v_cvt_pk_bf16_f32 %0, %1, %2" : "=v"(pk[c][0]) : "v"(sc[c][0]), "v"(sc[c][1]));
        asm("v_cvt_pk_bf16_f32 %0, %1, %2" : "=v"(pk[c][1]) : "v"(sc[c][2]), "v"(sc[c][3]));
      }
      // ---- register permutation -> PV A-fragments pa[kk] (kv = kk*32 + g*8 + 0..7, q=j) ----
      // Routes (hand-verified): lo slot src group 2g&3, hi slot src (2g+1)&3, c = 2kk+(g>>1).
      // X16 sends pk[2kk+gh], X32/X48 send pk[2kk+(gh^1)]; receiver selects by own g.
      bf16x8 pa[2];
      #pragma unroll
      for (int kk = 0; kk < 2; ++kk){
        u32 a0 = pk[2*kk + gh][0],       a1 = pk[2*kk + gh][1];
        u32 b0 = pk[2*kk + (gh ^ 1)][0], b1 = pk[2*kk + (gh ^ 1)][1];
        u32 v16_0 = (u32)__shfl_xor((int)a0, 16), v16_1 = (u32)__shfl_xor((int)a1, 16);
        u32 v32_0 = (u32)__shfl_xor((int)b0, 32), v32_1 = (u32)__shfl_xor((int)b1, 32);
        u32 v48_0 = (u32)__shfl_xor((int)b0, 48), v48_1 = (u32)__shfl_xor((int)b1, 48);
        union { u32 uw[4]; bf16x8 v; } u;
        u.uw[0] = (g==0) ? pk[2*kk][0]   : (g==1) ? v48_0 : (g==2) ? v32_0 : v16_0;
        u.uw[1] = (g==0) ? pk[2*kk][1]   : (g==1) ? v48_1 : (g==2) ? v32_1 : v16_1;
        u.uw[2] = (g==0) ? v16_0 : (g==1) ? v32_0 : (g==2) ? v48_0 : pk[2*kk+1][0];
        u.uw[3] = (g==0) ? v16_1 : (g==1) ? v32_1 : (g==2) ? v48_1 : pk[2*kk+1][1];
        pa[kk] = u.v;
      }
      // ---- O += P V from swizzled LDS ----
      const u16* vs = Vs[cur];
      __builtin_amdgcn_s_setprio(1);
      #pragma unroll
      for (int dt = 0; dt < 8; ++dt){
        const u16* vp = vs + (dt*16 + j) * 64;
        #pragma unroll
        for (int kk = 0; kk < 2; ++kk){
          bf16x8 vf = *(const bf16x8*)(vp + (((kk*32) + lk) ^ sw));
          o_acc[dt] = __builtin_amdgcn_mfma_f32_16x16x32_bf16(pa[kk], vf, o_acc[dt], 0, 0, 0);
        }
      }
      __builtin_amdgcn_s_setprio(0);
      cur ^= 1;
    }
    // ---- epilogue: transport lrow to o_acc rows; ob[b][t][h*128+d] = O / l ----
    #pragma unroll
    for (int r = 0; r < 4; ++r){
      float ls  = __shfl(lrow, (lane & 48) | (g*4 + r));
      float inv = 1.0f / ls;
      int t = q0 + g*4 + r;
      size_t base = ((size_t)b * TT + t) * EMBED + h * HD;
      #pragma unroll
      for (int dt = 0; dt < 8; ++dt)
        ob[base + dt*16 + j] = f2b(o_acc[dt][r] * inv);
    }
  }
}

extern "C" void kernel_launch(void* const* d_in, const int* in_sizes, int n_in,
                              void* d_out, int out_size, void* d_ws, size_t ws_size,
                              hipStream_t stream){
  const float* x  = (const float*)d_in[0];
  const float* Wq = (const float*)d_in[1];
  const float* Wk = (const float*)d_in[2];
  const float* Wv = (const float*)d_in[3];
  const float* Wo = (const float*)d_in[4];

  char* ws = (char*)d_ws;
  size_t off = 0;
  auto alloc = [&](size_t bytes){ void* p = ws + off; off += (bytes + 255) & ~(size_t)255; return p; };
  u16* xb    = (u16*)alloc((size_t)MROWS * EMBED * 2);
  u16* Wqkvt = (u16*)alloc((size_t)3072 * EMBED * 2);        // rows: 0..2047 Wq, 2048..2559 Wk, 2560..3071 Wv
  u16* Wot   = (u16*)alloc((size_t)EMBED * EMBED * 2);
  u16* qkv   = (u16*)alloc((QELEMS + 2*KELEMS) * 2);          // q | k | v contiguous
  u16* vtb   = (u16*)alloc(KELEMS * 2);
  u16* ob    = (u16*)alloc((size_t)MROWS * EMBED * 2);

  u16* qb = qkv;
  u16* kb = qb + QELEMS;
  u16* vb = kb + KELEMS;

  cvt_f32_bf16<<<(MROWS*EMBED/4 + 255)/256, 256, 0, stream>>>(x, xb, MROWS*EMBED/4);
  trans_w2<<<dim3(EMBED/32, EMBED/32, 2), 256, 0, stream>>>(Wq, Wqkvt, Wo, Wot, EMBED, EMBED);
  trans_w2<<<dim3(512/32,   EMBED/32, 2), 256, 0, stream>>>(Wk, Wqkvt + (size_t)2048*EMBED,
                                                            Wv, Wqkvt + (size_t)2560*EMBED, EMBED, 512);

  gemm_bt<2><<<(MROWS/128)*(3072/128), 256, 0, stream>>>(xb, Wqkvt, qkv, 3072, EMBED);
  trans_v<<<4*64*BB*NKV, 256, 0, stream>>>(vb, vtb);

  attn_kernel<<<BB*NH*16, 256, 0, stream>>>(qb, kb, vtb, ob);

  gemm_bt<0><<<(MROWS/128)*(EMBED/128), 256, 0, stream>>>(ob, Wot, d_out, EMBED, EMBED);
}